// Round 8
// baseline (395.749 us; speedup 1.0000x reference)
//
#include <hip/hip_runtime.h>

// GraphSAGE link predictor. f16 intermediates, XCD-sliced aggregation, swapped-MFMA edge MLP.
// Layouts:
//  row-major f16:  x16/h2 (f16buf), h1
//  slice  f16:     xs/gs (xsbuf), agg (ags):  buf[(sl*N + node)*8 + d], sl=dim>>3, d=dim&7
// Pipeline:
//  kA: x16 + xs slices + deg hist
//  scan -> row ; cbinit ; k_coarse ; k_fine_sort  (CSR srcs, dst-sorted)
//  ags = segsum_slices(xs[src])     (k_gather_slice, sl=bid&7 -> XCD-resident 1.6MB table)
//  h1 = (ags*inv)@Wl1 + x16@Wr1 + bl1   (GEMM MODE0, A=slices, out row f16)
//  gs = h1@Wl2                           (GEMM MODE1, out slices)
//  ags = segsum_slices(gs[src])          (k_gather_slice)
//  h2 = h1@Wr2 + ags*inv + bl2           (GEMM MODE2, add from slices, out row f16)
//  out[e] = relu((h2[s]*h2[d])@W1+b1)@W2+b2  (MFMA swapped: D=[hid x edge], b1 in C-init)

typedef _Float16 f16x8 __attribute__((ext_vector_type(8)));
typedef float f32x4 __attribute__((ext_vector_type(4)));

union H4 { _Float16 h[4]; uint2 u; };
union H8 { _Float16 h[8]; uint4 u; };

__device__ inline float4 load4f(const _Float16* p) {
  H4 h; h.u = *(const uint2*)p;
  return make_float4((float)h.h[0], (float)h.h[1], (float)h.h[2], (float)h.h[3]);
}
__device__ inline uint2 pack4(float4 v) {
  H4 p;
  p.h[0] = (_Float16)v.x; p.h[1] = (_Float16)v.y;
  p.h[2] = (_Float16)v.z; p.h[3] = (_Float16)v.w;
  return p.u;
}

// ---------------- kA: f32->f16 (row + slices) + deg histogram ----------------
__global__ void kA_convert_hist(const float* __restrict__ x, _Float16* __restrict__ x16,
                                _Float16* __restrict__ xs, const int* __restrict__ dst,
                                int* __restrict__ deg, int N, int n4, int E) {
  int t = blockIdx.x * blockDim.x + threadIdx.x;
  if (t < n4) {
    float4 v = ((const float4*)x)[t];
    uint2 p = pack4(v);
    ((uint2*)x16)[t] = p;
    int node = t >> 4, q = t & 15;            // dims q*4 .. q*4+3
    int sl = q >> 1, d0 = (q & 1) * 4;
    *(uint2*)(xs + ((size_t)sl * N + node) * 8 + d0) = p;
  }
  if (t < E) atomicAdd(&deg[dst[t]], 1);
}

// ---------------- scans ----------------
__global__ void k_scan1(const int* __restrict__ deg, int* __restrict__ ex,
                        int* __restrict__ bsum, int N) {
  __shared__ int sm[256];
  int t = threadIdx.x, i = blockIdx.x * 256 + t;
  int v = (i < N) ? deg[i] : 0;
  sm[t] = v;
  __syncthreads();
  for (int s = 1; s < 256; s <<= 1) {
    int a = (t >= s) ? sm[t - s] : 0;
    __syncthreads();
    sm[t] += a;
    __syncthreads();
  }
  if (i < N) ex[i] = sm[t] - v;
  if (t == 255) bsum[blockIdx.x] = sm[255];
}

__global__ void k_scan2(int* __restrict__ bsum, int nb) {
  __shared__ int sm[1024];
  int t = threadIdx.x;
  int v = (t < nb) ? bsum[t] : 0;
  sm[t] = v;
  __syncthreads();
  for (int s = 1; s < 1024; s <<= 1) {
    int a = (t >= s) ? sm[t - s] : 0;
    __syncthreads();
    sm[t] += a;
    __syncthreads();
  }
  if (t < nb) bsum[t] = sm[t] - v;
}

__global__ void k_scan3(const int* __restrict__ bsum, int* __restrict__ row,
                        const int* __restrict__ ex, int N, int E) {
  int i = blockIdx.x * blockDim.x + threadIdx.x;
  if (i < N) row[i] = ex[i] + bsum[i >> 8];
  if (i == 0) row[N] = E;
}

__global__ void k_cbinit(const int* __restrict__ row, int* __restrict__ cbcursor,
                         int N, int ncb) {
  int b = threadIdx.x + blockIdx.x * blockDim.x;
  if (b < ncb) {
    int node = b << 8;
    cbcursor[b] = row[node < N ? node : N];
  }
}

// ---------------- pass A: bucket edges by dst>>8 into packed u64 streams ----------
__global__ __launch_bounds__(256) void k_coarse(
    const int* __restrict__ src, const int* __restrict__ dst,
    int* __restrict__ cbcursor, unsigned long long* __restrict__ ep, int E) {
  __shared__ int lh[512];
  const int t = threadIdx.x;
  const int chunk = (E + gridDim.x - 1) / gridDim.x;
  const int e0 = blockIdx.x * chunk;
  const int e1 = min(e0 + chunk, E);
  lh[t] = 0; lh[t + 256] = 0;
  __syncthreads();
  for (int e = e0 + t; e < e1; e += 256)
    atomicAdd(&lh[dst[e] >> 8], 1);
  __syncthreads();
  {
    int c0 = lh[t], c1 = lh[t + 256];
    int b0 = c0 ? atomicAdd(&cbcursor[t], c0) : 0;
    int b1 = c1 ? atomicAdd(&cbcursor[t + 256], c1) : 0;
    __syncthreads();
    lh[t] = b0; lh[t + 256] = b1;
  }
  __syncthreads();
  for (int e = e0 + t; e < e1; e += 256) {
    int d = dst[e];
    int pos = atomicAdd(&lh[d >> 8], 1);
    ep[pos] = ((unsigned long long)d << 32) | (unsigned)src[e];
  }
}

// ---------------- pass B: per-bucket LDS count-sort -> coalesced srcs ----------
#define FS_CAP 4608
__global__ __launch_bounds__(256) void k_fine_sort(
    const unsigned long long* __restrict__ ep, const int* __restrict__ row,
    int* __restrict__ srcs, int N, int E) {
  __shared__ int cnt[256];
  __shared__ int cur[256];
  __shared__ int sm[256];
  __shared__ int stage[FS_CAP];
  const int b = blockIdx.x;
  const int t = threadIdx.x;
  const int n0 = b << 8;
  const int n1 = min(n0 + 256, N);
  const int beg = row[n0];
  const int end = row[n1];
  const int M = end - beg;

  cnt[t] = 0;
  __syncthreads();
  for (int i = beg + t; i < end; i += 256) {
    int loc = (int)(ep[i] >> 32) & 255;
    atomicAdd(&cnt[loc], 1);
  }
  __syncthreads();
  int v = cnt[t];
  sm[t] = v;
  __syncthreads();
  for (int s = 1; s < 256; s <<= 1) {
    int a = (t >= s) ? sm[t - s] : 0;
    __syncthreads();
    sm[t] += a;
    __syncthreads();
  }
  cur[t] = sm[t] - v;
  __syncthreads();
  for (int i = beg + t; i < end; i += 256) {
    unsigned long long p = ep[i];
    int loc = (int)(p >> 32) & 255;
    int pos = atomicAdd(&cur[loc], 1);
    if (pos < FS_CAP) stage[pos] = (int)(unsigned)p;
    else srcs[beg + pos] = (int)(unsigned)p;   // statistically never
  }
  __syncthreads();
  const int m = min(M, FS_CAP);
  for (int i = t; i < m; i += 256) srcs[beg + i] = stage[i];
}

// ---------------- sliced aggregation: sl = bid&7 (XCD-affine), 1 lane/node ------
__global__ __launch_bounds__(256) void k_gather_slice(
    const _Float16* __restrict__ xs, const int* __restrict__ row,
    const int* __restrict__ srcs, _Float16* __restrict__ ags, int N) {
  const int sl = blockIdx.x & 7;
  const int node = (blockIdx.x >> 3) * 256 + threadIdx.x;
  if (node >= N) return;
  const _Float16* xsl = xs + (size_t)sl * N * 8;
  int beg = row[node], end = row[node + 1];
  float acc[8];
#pragma unroll
  for (int i = 0; i < 8; i++) acc[i] = 0.f;
  int k = beg;
  for (; k + 1 < end; k += 2) {
    int s0 = srcs[k], s1 = srcs[k + 1];
    H8 a, b;
    a.u = *(const uint4*)(xsl + (size_t)s0 * 8);
    b.u = *(const uint4*)(xsl + (size_t)s1 * 8);
#pragma unroll
    for (int i = 0; i < 8; i++) acc[i] += (float)a.h[i] + (float)b.h[i];
  }
  if (k < end) {
    H8 a; a.u = *(const uint4*)(xsl + (size_t)srcs[k] * 8);
#pragma unroll
    for (int i = 0; i < 8; i++) acc[i] += (float)a.h[i];
  }
  H8 o;
#pragma unroll
  for (int i = 0; i < 8; i++) o.h[i] = (_Float16)acc[i];
  *(uint4*)(ags + ((size_t)sl * N + node) * 8) = o.u;
}

// ---------------- tiled node GEMM (f16 in, f16 out): out[N][J] ----------------
// MODE 0 (h1): acc = A@W (A slices) ; *= inv ; += A2@Wb (row) ; += bias ; row out
// MODE 1 (g):  acc = A@W (row)                                ; slice out
// MODE 2 (h2): acc = A@W (row) ; += add(slices)*inv + bias    ; row out
template <int K, int J, int MODE>
__global__ __launch_bounds__(256) void k_node_gemm16(
    const _Float16* __restrict__ A, const _Float16* __restrict__ A2,
    const float* __restrict__ W, const float* __restrict__ Wb,
    const float* __restrict__ bias, const _Float16* __restrict__ add64,
    const int* __restrict__ deg, _Float16* __restrict__ outp, int N) {
  constexpr int JT = J / 4;
  constexpr int NT = 256 / JT;
  constexpr int NPT = 64 / NT;
  constexpr int BK = 16;
  __shared__ float At[BK][64];
  __shared__ float Wt[BK][J];

  const int t = threadIdx.x;
  const int jt = t % JT, nt = t / JT;
  const int j0 = jt * 4, n0 = nt * NPT;
  const int nbase = blockIdx.x * 64;

  float4 acc[NPT];
#pragma unroll
  for (int r = 0; r < NPT; r++) acc[r] = make_float4(0.f, 0.f, 0.f, 0.f);

  auto phase = [&](const _Float16* __restrict__ S, const float* __restrict__ Wm,
                   bool slice) {
    for (int kb = 0; kb < K; kb += BK) {
      {
        int n = t >> 2, kq = t & 3;
        int node = nbase + n;
        int nclamp = node < N ? node : N - 1;
        float4 v;
        if (slice) {
          int k0 = kb + kq * 4;
          int sl = k0 >> 3, d0 = k0 & 7;
          v = load4f(S + ((size_t)sl * N + nclamp) * 8 + d0);
        } else {
          v = load4f(S + (size_t)nclamp * K + kb + kq * 4);
        }
        At[kq * 4 + 0][n] = v.x;
        At[kq * 4 + 1][n] = v.y;
        At[kq * 4 + 2][n] = v.z;
        At[kq * 4 + 3][n] = v.w;
      }
      {
        const float* wsrc = Wm + (size_t)kb * J;
        float* wdst = &Wt[0][0];
#pragma unroll
        for (int p = 0; p < (BK * J) / (256 * 4); p++) {
          int idx = (t + p * 256) * 4;
          *(float4*)(wdst + idx) = *(const float4*)(wsrc + idx);
        }
      }
      __syncthreads();
#pragma unroll
      for (int kk = 0; kk < BK; kk++) {
        float4 w = *(const float4*)&Wt[kk][j0];
        float av[NPT];
#pragma unroll
        for (int rq = 0; rq < NPT / 4; rq++) {
          float4 a = *(const float4*)&At[kk][n0 + rq * 4];
          av[rq * 4 + 0] = a.x;
          av[rq * 4 + 1] = a.y;
          av[rq * 4 + 2] = a.z;
          av[rq * 4 + 3] = a.w;
        }
#pragma unroll
        for (int r = 0; r < NPT; r++) {
          acc[r].x += av[r] * w.x;
          acc[r].y += av[r] * w.y;
          acc[r].z += av[r] * w.z;
          acc[r].w += av[r] * w.w;
        }
      }
      __syncthreads();
    }
  };

  phase(A, W, MODE == 0);

  if constexpr (MODE == 0) {
#pragma unroll
    for (int r = 0; r < NPT; r++) {
      int node = nbase + n0 + r;
      float inv = (node < N) ? 1.0f / fmaxf((float)deg[node], 1.0f) : 1.f;
      acc[r].x *= inv; acc[r].y *= inv; acc[r].z *= inv; acc[r].w *= inv;
    }
    phase(A2, Wb, false);
    float4 b = *(const float4*)&bias[j0];
#pragma unroll
    for (int r = 0; r < NPT; r++) {
      acc[r].x += b.x; acc[r].y += b.y; acc[r].z += b.z; acc[r].w += b.w;
    }
  }
  if constexpr (MODE == 2) {
    float4 b = *(const float4*)&bias[j0];
    const int sl = j0 >> 3, d0 = j0 & 7;
#pragma unroll
    for (int r = 0; r < NPT; r++) {
      int node = nbase + n0 + r;
      if (node < N) {
        float inv = 1.0f / fmaxf((float)deg[node], 1.0f);
        float4 ad = load4f(add64 + ((size_t)sl * N + node) * 8 + d0);
        acc[r].x += ad.x * inv + b.x;
        acc[r].y += ad.y * inv + b.y;
        acc[r].z += ad.z * inv + b.z;
        acc[r].w += ad.w * inv + b.w;
      }
    }
  }

#pragma unroll
  for (int r = 0; r < NPT; r++) {
    int node = nbase + n0 + r;
    if (node < N) {
      if constexpr (MODE == 1) {   // slice-layout output
        int sl = j0 >> 3, d0 = j0 & 7;
        *(uint2*)(outp + ((size_t)sl * N + node) * 8 + d0) = pack4(acc[r]);
      } else {
        *(uint2*)(outp + (size_t)node * J + j0) = pack4(acc[r]);
      }
    }
  }
}

// ---------------- edge MLP: swapped MFMA, D=[hid x edge] ----------------
// A = W1-tile^T fragments (same data as before), B = ev fragments.
// D col = lane&15 = edge, row = (lane>>4)*4+reg = hid (within tt*16 tile).
__global__ __launch_bounds__(256) void k_edge_mfma(
    const _Float16* __restrict__ h2, const int* __restrict__ src,
    const int* __restrict__ dst,
    const float* __restrict__ W1, const float* __restrict__ W2,
    const float* __restrict__ b1, const float* __restrict__ b2,
    float* __restrict__ out, int E) {
  const int gtid = blockIdx.x * blockDim.x + threadIdx.x;
  const int wave = gtid >> 6;
  const int nwaves = (gridDim.x * blockDim.x) >> 6;
  const int l = threadIdx.x & 63;
  const int col = l & 15;
  const int kb = (l >> 4) * 8;
  const int hb = (l >> 4) * 4;
  const int ngroups = (E + 15) / 16;
  const int gpw = (ngroups + nwaves - 1) / nwaves;
  const int g0 = wave * gpw;
  const int g1 = min(g0 + gpw, ngroups);
  if (g0 >= ngroups) return;

  f16x8 afrag[8][2];
#pragma unroll
  for (int tt = 0; tt < 8; tt++)
#pragma unroll
    for (int s = 0; s < 2; s++) {
      f16x8 bf;
#pragma unroll
      for (int e = 0; e < 8; e++)
        bf[e] = (_Float16)W1[(size_t)(s * 32 + kb + e) * 128 + tt * 16 + col];
      afrag[tt][s] = bf;
    }
  float4 c0[8], w2v[8];
#pragma unroll
  for (int tt = 0; tt < 8; tt++) {
    int hbase = tt * 16 + hb;
    c0[tt]  = make_float4(b1[hbase], b1[hbase + 1], b1[hbase + 2], b1[hbase + 3]);
    w2v[tt] = make_float4(W2[hbase], W2[hbase + 1], W2[hbase + 2], W2[hbase + 3]);
  }
  const float b2v = b2[0];

  auto ldrows = [&](int g, f16x8& a0, f16x8& a1) {
    int pos = g * 16 + col;
    if (pos >= E) pos = E - 1;
    int sp = src[pos], dp = dst[pos];
    f16x8 as0 = *(const f16x8*)(h2 + (size_t)sp * 64 + kb);
    f16x8 ad0 = *(const f16x8*)(h2 + (size_t)dp * 64 + kb);
    f16x8 as1 = *(const f16x8*)(h2 + (size_t)sp * 64 + 32 + kb);
    f16x8 ad1 = *(const f16x8*)(h2 + (size_t)dp * 64 + 32 + kb);
    a0 = as0 * ad0;
    a1 = as1 * ad1;
  };

  auto compute = [&](int g, f16x8 a0, f16x8 a1) {
    float psum = 0.f;
#pragma unroll
    for (int tt = 0; tt < 8; tt++) {
      f32x4 acc = {c0[tt].x, c0[tt].y, c0[tt].z, c0[tt].w};
      acc = __builtin_amdgcn_mfma_f32_16x16x32_f16(afrag[tt][0], a0, acc, 0, 0, 0);
      acc = __builtin_amdgcn_mfma_f32_16x16x32_f16(afrag[tt][1], a1, acc, 0, 0, 0);
      psum += fmaxf(acc[0], 0.f) * w2v[tt].x + fmaxf(acc[1], 0.f) * w2v[tt].y
            + fmaxf(acc[2], 0.f) * w2v[tt].z + fmaxf(acc[3], 0.f) * w2v[tt].w;
    }
    psum += __shfl_xor(psum, 16, 64);
    psum += __shfl_xor(psum, 32, 64);
    if (l < 16) {
      int epos = g * 16 + l;
      if (epos < E) out[epos] = psum + b2v;
    }
  };

  f16x8 a0, a1, na0, na1;
  ldrows(g0, a0, a1);
  for (int g = g0; g < g1; g++) {
    if (g + 1 < g1) ldrows(g + 1, na0, na1);
    compute(g, a0, a1);
    a0 = na0; a1 = na1;
  }
}

// ---------------- launch ----------------
extern "C" void kernel_launch(void* const* d_in, const int* in_sizes, int n_in,
                              void* d_out, int out_size, void* d_ws, size_t ws_size,
                              hipStream_t stream) {
  const float* x   = (const float*)d_in[0];
  const int*   ei  = (const int*)d_in[1];
  const float* Wl1 = (const float*)d_in[2];
  const float* bl1 = (const float*)d_in[3];
  const float* Wr1 = (const float*)d_in[4];
  const float* Wl2 = (const float*)d_in[5];
  const float* bl2 = (const float*)d_in[6];
  const float* Wr2 = (const float*)d_in[7];
  const float* W1  = (const float*)d_in[8];
  const float* b1  = (const float*)d_in[9];
  const float* W2  = (const float*)d_in[10];
  const float* b2  = (const float*)d_in[11];
  const int N = in_sizes[0] / 64;
  const int E = in_sizes[1] / 2;
  const int* src = ei;
  const int* dstp = ei + E;

  char* w = (char*)d_ws;
  size_t off = 0;
  auto alloc = [&](size_t bytes) -> void* {
    void* p = w + off;
    off = (off + bytes + 255) & ~(size_t)255;
    return p;
  };
  int*      deg      = (int*)alloc((size_t)N * 4);
  int*      row      = (int*)alloc((size_t)(N + 1) * 4);
  int*      ex       = (int*)alloc((size_t)N * 4);
  int*      bsum     = (int*)alloc(1024 * 4);
  int*      cbcursor = (int*)alloc(512 * 4);
  int*      srcs     = (int*)alloc((size_t)E * 4);
  unsigned long long* ep = (unsigned long long*)alloc((size_t)E * 8);
  _Float16* f16buf   = (_Float16*)alloc((size_t)N * 64 * 2);   // x16 row -> h2 row
  _Float16* xsbuf    = (_Float16*)alloc((size_t)N * 64 * 2);   // x slices -> g slices
  _Float16* ags      = (_Float16*)alloc((size_t)N * 64 * 2);   // agg slices (both rounds)
  _Float16* h1_16    = (_Float16*)alloc((size_t)N * 128 * 2);

  const int ncb = (N + 255) >> 8;

  hipMemsetAsync(deg, 0, (size_t)N * 4, stream);
  int n4 = N * 16;
  int kag = (max(n4, E) + 255) / 256;
  kA_convert_hist<<<kag, 256, 0, stream>>>(x, f16buf, xsbuf, dstp, deg, N, n4, E);
  int nb = (N + 255) / 256;
  k_scan1<<<nb, 256, 0, stream>>>(deg, ex, bsum, N);
  k_scan2<<<1, 1024, 0, stream>>>(bsum, nb);
  k_scan3<<<nb, 256, 0, stream>>>(bsum, row, ex, N, E);
  k_cbinit<<<2, 256, 0, stream>>>(row, cbcursor, N, ncb);
  k_coarse<<<256, 256, 0, stream>>>(src, dstp, cbcursor, ep, E);
  k_fine_sort<<<ncb, 256, 0, stream>>>(ep, row, srcs, N, E);

  int ngrid = (N + 63) / 64;
  int sgrid = 8 * ((N + 255) / 256);
  k_gather_slice<<<sgrid, 256, 0, stream>>>(xsbuf, row, srcs, ags, N);
  k_node_gemm16<64, 128, 0><<<ngrid, 256, 0, stream>>>(
      ags, f16buf, Wl1, Wr1, bl1, nullptr, deg, h1_16, N);
  k_node_gemm16<128, 64, 1><<<ngrid, 256, 0, stream>>>(
      h1_16, nullptr, Wl2, nullptr, nullptr, nullptr, nullptr, xsbuf, N);
  k_gather_slice<<<sgrid, 256, 0, stream>>>(xsbuf, row, srcs, ags, N);
  k_node_gemm16<128, 64, 2><<<ngrid, 256, 0, stream>>>(
      h1_16, nullptr, Wr2, nullptr, bl2, ags, deg, f16buf, N);
  k_edge_mfma<<<4096, 256, 0, stream>>>(f16buf, src, dstp, W1, W2, b1, b2,
                                        (float*)d_out, E);
}

// Round 9
// 337.339 us; speedup vs baseline: 1.1732x; 1.1732x over previous
//
#include <hip/hip_runtime.h>

// GraphSAGE link predictor. f16 row-major intermediates, 2-pass CSR bucket,
// swapped-MFMA edge MLP.
// Pipeline:
//  kA: x16 = f16(x) + deg hist (fused)
//  scan -> row ; cbinit ; k_coarse ; k_fine_sort (CSR srcs, dst-sorted, coalesced)
//  agg16 = f16(segsum(x16[src]))            (gather, 8 lanes/row, f32 accum)
//  h1 = (agg*inv)@Wl1 + x16@Wr1 + bl1       (tiled GEMM MODE0, f16 out)
//  g16 = h1@Wl2                             (tiled GEMM MODE1, f16 out)
//  agg16 = f16(segsum(g16[src]))            (gather)
//  h2 = h1@Wr2 + agg*inv + bl2              (tiled GEMM MODE2, f16 out)
//  out[e] = relu((h2[s]*h2[d])@W1+b1)@W2+b2 (MFMA swapped D=[hid x edge], b1 in C-init)

typedef _Float16 f16x8 __attribute__((ext_vector_type(8)));
typedef float f32x4 __attribute__((ext_vector_type(4)));

union H4 { _Float16 h[4]; uint2 u; };
union H8 { _Float16 h[8]; uint4 u; };

__device__ inline float4 load4f(const _Float16* p) {
  H4 h; h.u = *(const uint2*)p;
  return make_float4((float)h.h[0], (float)h.h[1], (float)h.h[2], (float)h.h[3]);
}
__device__ inline uint2 pack4(float4 v) {
  H4 p;
  p.h[0] = (_Float16)v.x; p.h[1] = (_Float16)v.y;
  p.h[2] = (_Float16)v.z; p.h[3] = (_Float16)v.w;
  return p.u;
}

// ---------------- kA: f32->f16 convert + deg histogram ----------------
__global__ void kA_convert_hist(const float* __restrict__ x, _Float16* __restrict__ x16,
                                const int* __restrict__ dst, int* __restrict__ deg,
                                int n4, int E) {
  int t = blockIdx.x * blockDim.x + threadIdx.x;
  if (t < n4) {
    float4 v = ((const float4*)x)[t];
    ((uint2*)x16)[t] = pack4(v);
  }
  if (t < E) atomicAdd(&deg[dst[t]], 1);
}

// ---------------- scans ----------------
__global__ void k_scan1(const int* __restrict__ deg, int* __restrict__ ex,
                        int* __restrict__ bsum, int N) {
  __shared__ int sm[256];
  int t = threadIdx.x, i = blockIdx.x * 256 + t;
  int v = (i < N) ? deg[i] : 0;
  sm[t] = v;
  __syncthreads();
  for (int s = 1; s < 256; s <<= 1) {
    int a = (t >= s) ? sm[t - s] : 0;
    __syncthreads();
    sm[t] += a;
    __syncthreads();
  }
  if (i < N) ex[i] = sm[t] - v;
  if (t == 255) bsum[blockIdx.x] = sm[255];
}

__global__ void k_scan2(int* __restrict__ bsum, int nb) {
  __shared__ int sm[1024];
  int t = threadIdx.x;
  int v = (t < nb) ? bsum[t] : 0;
  sm[t] = v;
  __syncthreads();
  for (int s = 1; s < 1024; s <<= 1) {
    int a = (t >= s) ? sm[t - s] : 0;
    __syncthreads();
    sm[t] += a;
    __syncthreads();
  }
  if (t < nb) bsum[t] = sm[t] - v;
}

__global__ void k_scan3(const int* __restrict__ bsum, int* __restrict__ row,
                        const int* __restrict__ ex, int N, int E) {
  int i = blockIdx.x * blockDim.x + threadIdx.x;
  if (i < N) row[i] = ex[i] + bsum[i >> 8];
  if (i == 0) row[N] = E;
}

__global__ void k_cbinit(const int* __restrict__ row, int* __restrict__ cbcursor,
                         int N, int ncb) {
  int b = threadIdx.x + blockIdx.x * blockDim.x;
  if (b < ncb) {
    int node = b << 8;
    cbcursor[b] = row[node < N ? node : N];
  }
}

// ---------------- pass A: bucket edges by dst>>8 into packed u64 streams ----------
__global__ __launch_bounds__(256) void k_coarse(
    const int* __restrict__ src, const int* __restrict__ dst,
    int* __restrict__ cbcursor, unsigned long long* __restrict__ ep, int E) {
  __shared__ int lh[512];
  const int t = threadIdx.x;
  const int chunk = (E + gridDim.x - 1) / gridDim.x;
  const int e0 = blockIdx.x * chunk;
  const int e1 = min(e0 + chunk, E);
  lh[t] = 0; lh[t + 256] = 0;
  __syncthreads();
  for (int e = e0 + t; e < e1; e += 256)
    atomicAdd(&lh[dst[e] >> 8], 1);
  __syncthreads();
  {
    int c0 = lh[t], c1 = lh[t + 256];
    int b0 = c0 ? atomicAdd(&cbcursor[t], c0) : 0;
    int b1 = c1 ? atomicAdd(&cbcursor[t + 256], c1) : 0;
    __syncthreads();
    lh[t] = b0; lh[t + 256] = b1;
  }
  __syncthreads();
  for (int e = e0 + t; e < e1; e += 256) {
    int d = dst[e];
    int pos = atomicAdd(&lh[d >> 8], 1);
    ep[pos] = ((unsigned long long)d << 32) | (unsigned)src[e];
  }
}

// ---------------- pass B: per-bucket LDS count-sort -> coalesced srcs ----------
#define FS_CAP 4608
__global__ __launch_bounds__(256) void k_fine_sort(
    const unsigned long long* __restrict__ ep, const int* __restrict__ row,
    int* __restrict__ srcs, int N, int E) {
  __shared__ int cnt[256];
  __shared__ int cur[256];
  __shared__ int sm[256];
  __shared__ int stage[FS_CAP];
  const int b = blockIdx.x;
  const int t = threadIdx.x;
  const int n0 = b << 8;
  const int n1 = min(n0 + 256, N);
  const int beg = row[n0];
  const int end = row[n1];
  const int M = end - beg;

  cnt[t] = 0;
  __syncthreads();
  for (int i = beg + t; i < end; i += 256) {
    int loc = (int)(ep[i] >> 32) & 255;
    atomicAdd(&cnt[loc], 1);
  }
  __syncthreads();
  int v = cnt[t];
  sm[t] = v;
  __syncthreads();
  for (int s = 1; s < 256; s <<= 1) {
    int a = (t >= s) ? sm[t - s] : 0;
    __syncthreads();
    sm[t] += a;
    __syncthreads();
  }
  cur[t] = sm[t] - v;
  __syncthreads();
  for (int i = beg + t; i < end; i += 256) {
    unsigned long long p = ep[i];
    int loc = (int)(p >> 32) & 255;
    int pos = atomicAdd(&cur[loc], 1);
    if (pos < FS_CAP) stage[pos] = (int)(unsigned)p;
    else srcs[beg + pos] = (int)(unsigned)p;   // statistically never
  }
  __syncthreads();
  const int m = min(M, FS_CAP);
  for (int i = t; i < m; i += 256) srcs[beg + i] = stage[i];
}

// ---------------- aggregation: 8 lanes/row (16B each), unroll 4, f16 out --------
__global__ __launch_bounds__(256) void k_gather16(
    const _Float16* __restrict__ feat, const int* __restrict__ row,
    const int* __restrict__ srcs, _Float16* __restrict__ agg, int N) {
  int tid = blockIdx.x * blockDim.x + threadIdx.x;
  int node = tid >> 3, slot = tid & 7;
  if (node >= N) return;
  int beg = row[node], end = row[node + 1];
  float acc[8];
#pragma unroll
  for (int i = 0; i < 8; i++) acc[i] = 0.f;
  int k = beg;
  for (; k + 3 < end; k += 4) {
    int s0 = srcs[k], s1 = srcs[k + 1], s2 = srcs[k + 2], s3 = srcs[k + 3];
    H8 a, b, c, d;
    a.u = *(const uint4*)(feat + (size_t)s0 * 64 + slot * 8);
    b.u = *(const uint4*)(feat + (size_t)s1 * 64 + slot * 8);
    c.u = *(const uint4*)(feat + (size_t)s2 * 64 + slot * 8);
    d.u = *(const uint4*)(feat + (size_t)s3 * 64 + slot * 8);
#pragma unroll
    for (int i = 0; i < 8; i++)
      acc[i] += ((float)a.h[i] + (float)b.h[i]) + ((float)c.h[i] + (float)d.h[i]);
  }
  for (; k < end; k++) {
    H8 a; a.u = *(const uint4*)(feat + (size_t)srcs[k] * 64 + slot * 8);
#pragma unroll
    for (int i = 0; i < 8; i++) acc[i] += (float)a.h[i];
  }
  H8 o;
#pragma unroll
  for (int i = 0; i < 8; i++) o.h[i] = (_Float16)acc[i];
  *(uint4*)(agg + (size_t)node * 64 + slot * 8) = o.u;
}

// ---------------- tiled node GEMM (f16 in, f16 out): out[N][J] ----------------
template <int K, int J, int MODE>
__global__ __launch_bounds__(256) void k_node_gemm16(
    const _Float16* __restrict__ A, const _Float16* __restrict__ A2,
    const float* __restrict__ W, const float* __restrict__ Wb,
    const float* __restrict__ bias, const _Float16* __restrict__ add64,
    const int* __restrict__ deg, _Float16* __restrict__ outp, int N) {
  constexpr int JT = J / 4;
  constexpr int NT = 256 / JT;
  constexpr int NPT = 64 / NT;
  constexpr int BK = 16;
  __shared__ float At[BK][64];
  __shared__ float Wt[BK][J];

  const int t = threadIdx.x;
  const int jt = t % JT, nt = t / JT;
  const int j0 = jt * 4, n0 = nt * NPT;
  const int nbase = blockIdx.x * 64;

  float4 acc[NPT];
#pragma unroll
  for (int r = 0; r < NPT; r++) acc[r] = make_float4(0.f, 0.f, 0.f, 0.f);

  auto phase = [&](const _Float16* __restrict__ S, const float* __restrict__ Wm) {
    for (int kb = 0; kb < K; kb += BK) {
      {
        int n = t >> 2, kq = t & 3;
        int node = nbase + n;
        int nclamp = node < N ? node : N - 1;
        float4 v = load4f(S + (size_t)nclamp * K + kb + kq * 4);
        At[kq * 4 + 0][n] = v.x;
        At[kq * 4 + 1][n] = v.y;
        At[kq * 4 + 2][n] = v.z;
        At[kq * 4 + 3][n] = v.w;
      }
      {
        const float* wsrc = Wm + (size_t)kb * J;
        float* wdst = &Wt[0][0];
#pragma unroll
        for (int p = 0; p < (BK * J) / (256 * 4); p++) {
          int idx = (t + p * 256) * 4;
          *(float4*)(wdst + idx) = *(const float4*)(wsrc + idx);
        }
      }
      __syncthreads();
#pragma unroll
      for (int kk = 0; kk < BK; kk++) {
        float4 w = *(const float4*)&Wt[kk][j0];
        float av[NPT];
#pragma unroll
        for (int rq = 0; rq < NPT / 4; rq++) {
          float4 a = *(const float4*)&At[kk][n0 + rq * 4];
          av[rq * 4 + 0] = a.x;
          av[rq * 4 + 1] = a.y;
          av[rq * 4 + 2] = a.z;
          av[rq * 4 + 3] = a.w;
        }
#pragma unroll
        for (int r = 0; r < NPT; r++) {
          acc[r].x += av[r] * w.x;
          acc[r].y += av[r] * w.y;
          acc[r].z += av[r] * w.z;
          acc[r].w += av[r] * w.w;
        }
      }
      __syncthreads();
    }
  };

  phase(A, W);

  if constexpr (MODE == 0) {
#pragma unroll
    for (int r = 0; r < NPT; r++) {
      int node = nbase + n0 + r;
      float inv = (node < N) ? 1.0f / fmaxf((float)deg[node], 1.0f) : 1.f;
      acc[r].x *= inv; acc[r].y *= inv; acc[r].z *= inv; acc[r].w *= inv;
    }
    phase(A2, Wb);
    float4 b = *(const float4*)&bias[j0];
#pragma unroll
    for (int r = 0; r < NPT; r++) {
      acc[r].x += b.x; acc[r].y += b.y; acc[r].z += b.z; acc[r].w += b.w;
    }
  }
  if constexpr (MODE == 2) {
    float4 b = *(const float4*)&bias[j0];
#pragma unroll
    for (int r = 0; r < NPT; r++) {
      int node = nbase + n0 + r;
      if (node < N) {
        float inv = 1.0f / fmaxf((float)deg[node], 1.0f);
        float4 ad = load4f(add64 + (size_t)node * J + j0);
        acc[r].x += ad.x * inv + b.x;
        acc[r].y += ad.y * inv + b.y;
        acc[r].z += ad.z * inv + b.z;
        acc[r].w += ad.w * inv + b.w;
      }
    }
  }

#pragma unroll
  for (int r = 0; r < NPT; r++) {
    int node = nbase + n0 + r;
    if (node < N)
      *(uint2*)(outp + (size_t)node * J + j0) = pack4(acc[r]);
  }
}

// ---------------- edge MLP: swapped MFMA, D=[hid x edge], b1 in C-init ----------
__global__ __launch_bounds__(256) void k_edge_mfma(
    const _Float16* __restrict__ h2, const int* __restrict__ src,
    const int* __restrict__ dst,
    const float* __restrict__ W1, const float* __restrict__ W2,
    const float* __restrict__ b1, const float* __restrict__ b2,
    float* __restrict__ out, int E) {
  const int gtid = blockIdx.x * blockDim.x + threadIdx.x;
  const int wave = gtid >> 6;
  const int nwaves = (gridDim.x * blockDim.x) >> 6;
  const int l = threadIdx.x & 63;
  const int col = l & 15;
  const int kb = (l >> 4) * 8;
  const int hb = (l >> 4) * 4;
  const int ngroups = (E + 15) / 16;
  const int gpw = (ngroups + nwaves - 1) / nwaves;
  const int g0 = wave * gpw;
  const int g1 = min(g0 + gpw, ngroups);
  if (g0 >= ngroups) return;

  f16x8 afrag[8][2];
#pragma unroll
  for (int tt = 0; tt < 8; tt++)
#pragma unroll
    for (int s = 0; s < 2; s++) {
      f16x8 bf;
#pragma unroll
      for (int e = 0; e < 8; e++)
        bf[e] = (_Float16)W1[(size_t)(s * 32 + kb + e) * 128 + tt * 16 + col];
      afrag[tt][s] = bf;
    }
  float4 c0[8], w2v[8];
#pragma unroll
  for (int tt = 0; tt < 8; tt++) {
    int hbase = tt * 16 + hb;
    c0[tt]  = make_float4(b1[hbase], b1[hbase + 1], b1[hbase + 2], b1[hbase + 3]);
    w2v[tt] = make_float4(W2[hbase], W2[hbase + 1], W2[hbase + 2], W2[hbase + 3]);
  }
  const float b2v = b2[0];

  auto ldrows = [&](int g, f16x8& a0, f16x8& a1) {
    int pos = g * 16 + col;
    if (pos >= E) pos = E - 1;
    int sp = src[pos], dp = dst[pos];
    f16x8 as0 = *(const f16x8*)(h2 + (size_t)sp * 64 + kb);
    f16x8 ad0 = *(const f16x8*)(h2 + (size_t)dp * 64 + kb);
    f16x8 as1 = *(const f16x8*)(h2 + (size_t)sp * 64 + 32 + kb);
    f16x8 ad1 = *(const f16x8*)(h2 + (size_t)dp * 64 + 32 + kb);
    a0 = as0 * ad0;
    a1 = as1 * ad1;
  };

  auto compute = [&](int g, f16x8 a0, f16x8 a1) {
    float psum = 0.f;
#pragma unroll
    for (int tt = 0; tt < 8; tt++) {
      f32x4 acc = {c0[tt].x, c0[tt].y, c0[tt].z, c0[tt].w};
      acc = __builtin_amdgcn_mfma_f32_16x16x32_f16(afrag[tt][0], a0, acc, 0, 0, 0);
      acc = __builtin_amdgcn_mfma_f32_16x16x32_f16(afrag[tt][1], a1, acc, 0, 0, 0);
      psum += fmaxf(acc[0], 0.f) * w2v[tt].x + fmaxf(acc[1], 0.f) * w2v[tt].y
            + fmaxf(acc[2], 0.f) * w2v[tt].z + fmaxf(acc[3], 0.f) * w2v[tt].w;
    }
    psum += __shfl_xor(psum, 16, 64);
    psum += __shfl_xor(psum, 32, 64);
    if (l < 16) {
      int epos = g * 16 + l;
      if (epos < E) out[epos] = psum + b2v;
    }
  };

  f16x8 a0, a1, na0, na1;
  ldrows(g0, a0, a1);
  for (int g = g0; g < g1; g++) {
    if (g + 1 < g1) ldrows(g + 1, na0, na1);
    compute(g, a0, a1);
    a0 = na0; a1 = na1;
  }
}

// ---------------- launch ----------------
extern "C" void kernel_launch(void* const* d_in, const int* in_sizes, int n_in,
                              void* d_out, int out_size, void* d_ws, size_t ws_size,
                              hipStream_t stream) {
  const float* x   = (const float*)d_in[0];
  const int*   ei  = (const int*)d_in[1];
  const float* Wl1 = (const float*)d_in[2];
  const float* bl1 = (const float*)d_in[3];
  const float* Wr1 = (const float*)d_in[4];
  const float* Wl2 = (const float*)d_in[5];
  const float* bl2 = (const float*)d_in[6];
  const float* Wr2 = (const float*)d_in[7];
  const float* W1  = (const float*)d_in[8];
  const float* b1  = (const float*)d_in[9];
  const float* W2  = (const float*)d_in[10];
  const float* b2  = (const float*)d_in[11];
  const int N = in_sizes[0] / 64;
  const int E = in_sizes[1] / 2;
  const int* src = ei;
  const int* dstp = ei + E;

  char* w = (char*)d_ws;
  size_t off = 0;
  auto alloc = [&](size_t bytes) -> void* {
    void* p = w + off;
    off = (off + bytes + 255) & ~(size_t)255;
    return p;
  };
  int*      deg      = (int*)alloc((size_t)N * 4);
  int*      row      = (int*)alloc((size_t)(N + 1) * 4);
  int*      ex       = (int*)alloc((size_t)N * 4);
  int*      bsum     = (int*)alloc(1024 * 4);
  int*      cbcursor = (int*)alloc(512 * 4);
  int*      srcs     = (int*)alloc((size_t)E * 4);
  unsigned long long* ep = (unsigned long long*)alloc((size_t)E * 8);
  _Float16* f16buf   = (_Float16*)alloc((size_t)N * 64 * 2);   // x16 -> g16 -> h2
  _Float16* agg16    = (_Float16*)alloc((size_t)N * 64 * 2);   // aggX -> aggG
  _Float16* h1_16    = (_Float16*)alloc((size_t)N * 128 * 2);

  const int ncb = (N + 255) >> 8;

  hipMemsetAsync(deg, 0, (size_t)N * 4, stream);
  int n4 = N * 16;
  int kag = (max(n4, E) + 255) / 256;
  kA_convert_hist<<<kag, 256, 0, stream>>>(x, f16buf, dstp, deg, n4, E);
  int nb = (N + 255) / 256;
  k_scan1<<<nb, 256, 0, stream>>>(deg, ex, bsum, N);
  k_scan2<<<1, 1024, 0, stream>>>(bsum, nb);
  k_scan3<<<nb, 256, 0, stream>>>(bsum, row, ex, N, E);
  k_cbinit<<<2, 256, 0, stream>>>(row, cbcursor, N, ncb);
  k_coarse<<<256, 256, 0, stream>>>(src, dstp, cbcursor, ep, E);
  k_fine_sort<<<ncb, 256, 0, stream>>>(ep, row, srcs, N, E);

  int ngrid = (N + 63) / 64;
  int ggrid = (N * 8 + 255) / 256;
  k_gather16<<<ggrid, 256, 0, stream>>>(f16buf, row, srcs, agg16, N);
  k_node_gemm16<64, 128, 0><<<ngrid, 256, 0, stream>>>(
      agg16, f16buf, Wl1, Wr1, bl1, nullptr, deg, h1_16, N);
  k_node_gemm16<128, 64, 1><<<ngrid, 256, 0, stream>>>(
      h1_16, nullptr, Wl2, nullptr, nullptr, nullptr, nullptr, f16buf, N);
  k_gather16<<<ggrid, 256, 0, stream>>>(f16buf, row, srcs, agg16, N);
  k_node_gemm16<128, 64, 2><<<ngrid, 256, 0, stream>>>(
      h1_16, nullptr, Wr2, nullptr, bl2, agg16, deg, f16buf, N);
  k_edge_mfma<<<4096, 256, 0, stream>>>(f16buf, src, dstp, W1, W2, b1, b2,
                                        (float*)d_out, E);
}

// Round 10
// 273.395 us; speedup vs baseline: 1.4475x; 1.2339x over previous
//
#include <hip/hip_runtime.h>

// GraphSAGE link predictor. f16 intermediates, 2-pass CSR bucket,
// MFMA node GEMMs, swapped-MFMA edge MLP.
// Pipeline:
//  kA: x16 = f16(x) + deg hist (fused)
//  scan -> row ; cbinit ; k_coarse ; k_fine_sort (CSR srcs, dst-sorted, coalesced)
//  agg16 = f16(segsum(x16[src]))            (gather, 8 lanes/row, f32 accum)
//  h1 = (agg*inv)@Wl1 + x16@Wr1 + bl1       (MFMA MODE0, f16 out)
//  g16 = h1@Wl2                             (MFMA MODE1, f16 out)
//  agg16 = f16(segsum(g16[src]))            (gather)
//  h2 = h1@Wr2 + agg*inv + bl2              (MFMA MODE2, f16 out)
//  out[e] = relu((h2[s]*h2[d])@W1+b1)@W2+b2 (MFMA swapped D=[hid x edge], b1 in C-init)

typedef _Float16 f16x8 __attribute__((ext_vector_type(8)));
typedef float f32x4 __attribute__((ext_vector_type(4)));

union H4 { _Float16 h[4]; uint2 u; };
union H8 { _Float16 h[8]; uint4 u; };

__device__ inline uint2 pack4(float4 v) {
  H4 p;
  p.h[0] = (_Float16)v.x; p.h[1] = (_Float16)v.y;
  p.h[2] = (_Float16)v.z; p.h[3] = (_Float16)v.w;
  return p.u;
}

// ---------------- kA: f32->f16 convert + deg histogram ----------------
__global__ void kA_convert_hist(const float* __restrict__ x, _Float16* __restrict__ x16,
                                const int* __restrict__ dst, int* __restrict__ deg,
                                int n4, int E) {
  int t = blockIdx.x * blockDim.x + threadIdx.x;
  if (t < n4) {
    float4 v = ((const float4*)x)[t];
    ((uint2*)x16)[t] = pack4(v);
  }
  if (t < E) atomicAdd(&deg[dst[t]], 1);
}

// ---------------- scans ----------------
__global__ void k_scan1(const int* __restrict__ deg, int* __restrict__ ex,
                        int* __restrict__ bsum, int N) {
  __shared__ int sm[256];
  int t = threadIdx.x, i = blockIdx.x * 256 + t;
  int v = (i < N) ? deg[i] : 0;
  sm[t] = v;
  __syncthreads();
  for (int s = 1; s < 256; s <<= 1) {
    int a = (t >= s) ? sm[t - s] : 0;
    __syncthreads();
    sm[t] += a;
    __syncthreads();
  }
  if (i < N) ex[i] = sm[t] - v;
  if (t == 255) bsum[blockIdx.x] = sm[255];
}

__global__ void k_scan2(int* __restrict__ bsum, int nb) {
  __shared__ int sm[1024];
  int t = threadIdx.x;
  int v = (t < nb) ? bsum[t] : 0;
  sm[t] = v;
  __syncthreads();
  for (int s = 1; s < 1024; s <<= 1) {
    int a = (t >= s) ? sm[t - s] : 0;
    __syncthreads();
    sm[t] += a;
    __syncthreads();
  }
  if (t < nb) bsum[t] = sm[t] - v;
}

__global__ void k_scan3(const int* __restrict__ bsum, int* __restrict__ row,
                        const int* __restrict__ ex, int N, int E) {
  int i = blockIdx.x * blockDim.x + threadIdx.x;
  if (i < N) row[i] = ex[i] + bsum[i >> 8];
  if (i == 0) row[N] = E;
}

__global__ void k_cbinit(const int* __restrict__ row, int* __restrict__ cbcursor,
                         int N, int ncb) {
  int b = threadIdx.x + blockIdx.x * blockDim.x;
  if (b < ncb) {
    int node = b << 8;
    cbcursor[b] = row[node < N ? node : N];
  }
}

// ---------------- pass A: bucket edges by dst>>8 into packed u64 streams ----------
__global__ __launch_bounds__(256) void k_coarse(
    const int* __restrict__ src, const int* __restrict__ dst,
    int* __restrict__ cbcursor, unsigned long long* __restrict__ ep, int E) {
  __shared__ int lh[512];
  const int t = threadIdx.x;
  const int chunk = (E + gridDim.x - 1) / gridDim.x;
  const int e0 = blockIdx.x * chunk;
  const int e1 = min(e0 + chunk, E);
  lh[t] = 0; lh[t + 256] = 0;
  __syncthreads();
  for (int e = e0 + t; e < e1; e += 256)
    atomicAdd(&lh[dst[e] >> 8], 1);
  __syncthreads();
  {
    int c0 = lh[t], c1 = lh[t + 256];
    int b0 = c0 ? atomicAdd(&cbcursor[t], c0) : 0;
    int b1 = c1 ? atomicAdd(&cbcursor[t + 256], c1) : 0;
    __syncthreads();
    lh[t] = b0; lh[t + 256] = b1;
  }
  __syncthreads();
  for (int e = e0 + t; e < e1; e += 256) {
    int d = dst[e];
    int pos = atomicAdd(&lh[d >> 8], 1);
    ep[pos] = ((unsigned long long)d << 32) | (unsigned)src[e];
  }
}

// ---------------- pass B: per-bucket LDS count-sort -> coalesced srcs ----------
#define FS_CAP 4608
__global__ __launch_bounds__(256) void k_fine_sort(
    const unsigned long long* __restrict__ ep, const int* __restrict__ row,
    int* __restrict__ srcs, int N, int E) {
  __shared__ int cnt[256];
  __shared__ int cur[256];
  __shared__ int sm[256];
  __shared__ int stage[FS_CAP];
  const int b = blockIdx.x;
  const int t = threadIdx.x;
  const int n0 = b << 8;
  const int n1 = min(n0 + 256, N);
  const int beg = row[n0];
  const int end = row[n1];
  const int M = end - beg;

  cnt[t] = 0;
  __syncthreads();
  for (int i = beg + t; i < end; i += 256) {
    int loc = (int)(ep[i] >> 32) & 255;
    atomicAdd(&cnt[loc], 1);
  }
  __syncthreads();
  int v = cnt[t];
  sm[t] = v;
  __syncthreads();
  for (int s = 1; s < 256; s <<= 1) {
    int a = (t >= s) ? sm[t - s] : 0;
    __syncthreads();
    sm[t] += a;
    __syncthreads();
  }
  cur[t] = sm[t] - v;
  __syncthreads();
  for (int i = beg + t; i < end; i += 256) {
    unsigned long long p = ep[i];
    int loc = (int)(p >> 32) & 255;
    int pos = atomicAdd(&cur[loc], 1);
    if (pos < FS_CAP) stage[pos] = (int)(unsigned)p;
    else srcs[beg + pos] = (int)(unsigned)p;   // statistically never
  }
  __syncthreads();
  const int m = min(M, FS_CAP);
  for (int i = t; i < m; i += 256) srcs[beg + i] = stage[i];
}

// ---------------- aggregation: 8 lanes/row (16B each), unroll 4, f16 out --------
__global__ __launch_bounds__(256) void k_gather16(
    const _Float16* __restrict__ feat, const int* __restrict__ row,
    const int* __restrict__ srcs, _Float16* __restrict__ agg, int N) {
  int tid = blockIdx.x * blockDim.x + threadIdx.x;
  int node = tid >> 3, slot = tid & 7;
  if (node >= N) return;
  int beg = row[node], end = row[node + 1];
  float acc[8];
#pragma unroll
  for (int i = 0; i < 8; i++) acc[i] = 0.f;
  int k = beg;
  for (; k + 3 < end; k += 4) {
    int s0 = srcs[k], s1 = srcs[k + 1], s2 = srcs[k + 2], s3 = srcs[k + 3];
    H8 a, b, c, d;
    a.u = *(const uint4*)(feat + (size_t)s0 * 64 + slot * 8);
    b.u = *(const uint4*)(feat + (size_t)s1 * 64 + slot * 8);
    c.u = *(const uint4*)(feat + (size_t)s2 * 64 + slot * 8);
    d.u = *(const uint4*)(feat + (size_t)s3 * 64 + slot * 8);
#pragma unroll
    for (int i = 0; i < 8; i++)
      acc[i] += ((float)a.h[i] + (float)b.h[i]) + ((float)c.h[i] + (float)d.h[i]);
  }
  for (; k < end; k++) {
    H8 a; a.u = *(const uint4*)(feat + (size_t)srcs[k] * 64 + slot * 8);
#pragma unroll
    for (int i = 0; i < 8; i++) acc[i] += (float)a.h[i];
  }
  H8 o;
#pragma unroll
  for (int i = 0; i < 8; i++) o.h[i] = (_Float16)acc[i];
  *(uint4*)(agg + (size_t)node * 64 + slot * 8) = o.u;
}

// ---------------- MFMA node GEMM: out[N][J] = f(A[N][K] @ W[K][J]) ----------------
// One wave per 16 nodes, 4 waves/block. A-frags direct from global (coalesced 64B
// lines); W frags preloaded in VGPRs; D layout col=lane&15 (j), row=(l>>4)*4+reg
// (node). Output staged via padded LDS for coalesced uint4 stores.
// MODE 0 (h1): acc = A@W ; *= inv(deg) ; += A2@Wb ; += bias
// MODE 1 (g):  acc = A@W
// MODE 2 (h2): acc = A@W ; += add64*inv(deg) + bias
template <int K, int J, int MODE>
__global__ __launch_bounds__(256) void k_node_mfma(
    const _Float16* __restrict__ A, const _Float16* __restrict__ A2,
    const float* __restrict__ W, const float* __restrict__ Wb,
    const float* __restrict__ bias, const _Float16* __restrict__ add64,
    const int* __restrict__ deg, _Float16* __restrict__ outp, int N) {
  constexpr int KS = K / 32;   // k-steps (2 or 4)
  constexpr int TT = J / 16;   // col tiles (8 or 4)
  constexpr int RU4 = J / 8;   // uint4 per output row
  __shared__ _Float16 ostage[4][16][J + 8];

  const int w = threadIdx.x >> 6;
  const int l = threadIdx.x & 63;
  const int col = l & 15;
  const int kb8 = (l >> 4) * 8;
  const int nb = blockIdx.x * 64 + w * 16;

  // preload W fragments (f32 -> f16): lane supplies B[k=kb8+e][j=tt*16+col]
  f16x8 wf[TT][KS];
#pragma unroll
  for (int tt = 0; tt < TT; tt++)
#pragma unroll
    for (int s = 0; s < KS; s++) {
      f16x8 v;
#pragma unroll
      for (int e = 0; e < 8; e++)
        v[e] = (_Float16)W[(size_t)(s * 32 + kb8 + e) * J + tt * 16 + col];
      wf[tt][s] = v;
    }

  // A-frags: lane supplies A[m = col][k = kb8+e] for the wave's 16 nodes
  const int nodeA = min(nb + col, N - 1);
  f16x8 af[KS];
#pragma unroll
  for (int s = 0; s < KS; s++)
    af[s] = *(const f16x8*)(A + (size_t)nodeA * K + s * 32 + kb8);

  f32x4 acc[TT];
#pragma unroll
  for (int tt = 0; tt < TT; tt++) {
    f32x4 a = {0.f, 0.f, 0.f, 0.f};
#pragma unroll
    for (int s = 0; s < KS; s++)
      a = __builtin_amdgcn_mfma_f32_16x16x32_f16(af[s], wf[tt][s], a, 0, 0, 0);
    acc[tt] = a;
  }

  if constexpr (MODE == 0) {
    float inv[4];
#pragma unroll
    for (int reg = 0; reg < 4; reg++) {
      int nd = min(nb + (l >> 4) * 4 + reg, N - 1);
      inv[reg] = 1.0f / fmaxf((float)deg[nd], 1.0f);
    }
#pragma unroll
    for (int tt = 0; tt < TT; tt++)
#pragma unroll
      for (int reg = 0; reg < 4; reg++) acc[tt][reg] *= inv[reg];

    // second weight set + second operand
    f16x8 wfb[TT][KS];
#pragma unroll
    for (int tt = 0; tt < TT; tt++)
#pragma unroll
      for (int s = 0; s < KS; s++) {
        f16x8 v;
#pragma unroll
        for (int e = 0; e < 8; e++)
          v[e] = (_Float16)Wb[(size_t)(s * 32 + kb8 + e) * J + tt * 16 + col];
        wfb[tt][s] = v;
      }
#pragma unroll
    for (int s = 0; s < KS; s++)
      af[s] = *(const f16x8*)(A2 + (size_t)nodeA * K + s * 32 + kb8);
#pragma unroll
    for (int tt = 0; tt < TT; tt++)
#pragma unroll
      for (int s = 0; s < KS; s++)
        acc[tt] = __builtin_amdgcn_mfma_f32_16x16x32_f16(af[s], wfb[tt][s], acc[tt], 0, 0, 0);

#pragma unroll
    for (int tt = 0; tt < TT; tt++) {
      float bl = bias[tt * 16 + col];
#pragma unroll
      for (int reg = 0; reg < 4; reg++) acc[tt][reg] += bl;
    }
  }

  if constexpr (MODE == 2) {
    float inv[4];
    int ndc[4];
#pragma unroll
    for (int reg = 0; reg < 4; reg++) {
      ndc[reg] = min(nb + (l >> 4) * 4 + reg, N - 1);
      inv[reg] = 1.0f / fmaxf((float)deg[ndc[reg]], 1.0f);
    }
#pragma unroll
    for (int tt = 0; tt < TT; tt++) {
      float bl = bias[tt * 16 + col];
#pragma unroll
      for (int reg = 0; reg < 4; reg++) {
        float ad = (float)add64[(size_t)ndc[reg] * J + tt * 16 + col];
        acc[tt][reg] += ad * inv[reg] + bl;
      }
    }
  }

  // stage D -> LDS (node-major), then coalesced uint4 global stores
#pragma unroll
  for (int tt = 0; tt < TT; tt++)
#pragma unroll
    for (int reg = 0; reg < 4; reg++)
      ostage[w][(l >> 4) * 4 + reg][tt * 16 + col] = (_Float16)acc[tt][reg];
  __syncthreads();
#pragma unroll
  for (int i = 0; i < J / 32; i++) {
    int idx = i * 64 + l;
    int r = idx / RU4, q = idx % RU4;
    int gn = nb + r;
    if (gn < N)
      *(uint4*)(outp + (size_t)gn * J + q * 8) = *(const uint4*)(&ostage[w][r][q * 8]);
  }
}

// ---------------- edge MLP: swapped MFMA, D=[hid x edge], b1 in C-init ----------
__global__ __launch_bounds__(256) void k_edge_mfma(
    const _Float16* __restrict__ h2, const int* __restrict__ src,
    const int* __restrict__ dst,
    const float* __restrict__ W1, const float* __restrict__ W2,
    const float* __restrict__ b1, const float* __restrict__ b2,
    float* __restrict__ out, int E) {
  const int gtid = blockIdx.x * blockDim.x + threadIdx.x;
  const int wave = gtid >> 6;
  const int nwaves = (gridDim.x * blockDim.x) >> 6;
  const int l = threadIdx.x & 63;
  const int col = l & 15;
  const int kb = (l >> 4) * 8;
  const int hb = (l >> 4) * 4;
  const int ngroups = (E + 15) / 16;
  const int gpw = (ngroups + nwaves - 1) / nwaves;
  const int g0 = wave * gpw;
  const int g1 = min(g0 + gpw, ngroups);
  if (g0 >= ngroups) return;

  f16x8 afrag[8][2];
#pragma unroll
  for (int tt = 0; tt < 8; tt++)
#pragma unroll
    for (int s = 0; s < 2; s++) {
      f16x8 bf;
#pragma unroll
      for (int e = 0; e < 8; e++)
        bf[e] = (_Float16)W1[(size_t)(s * 32 + kb + e) * 128 + tt * 16 + col];
      afrag[tt][s] = bf;
    }
  float4 c0[8], w2v[8];
#pragma unroll
  for (int tt = 0; tt < 8; tt++) {
    int hbase = tt * 16 + hb;
    c0[tt]  = make_float4(b1[hbase], b1[hbase + 1], b1[hbase + 2], b1[hbase + 3]);
    w2v[tt] = make_float4(W2[hbase], W2[hbase + 1], W2[hbase + 2], W2[hbase + 3]);
  }
  const float b2v = b2[0];

  auto ldrows = [&](int g, f16x8& a0, f16x8& a1) {
    int pos = g * 16 + col;
    if (pos >= E) pos = E - 1;
    int sp = src[pos], dp = dst[pos];
    f16x8 as0 = *(const f16x8*)(h2 + (size_t)sp * 64 + kb);
    f16x8 ad0 = *(const f16x8*)(h2 + (size_t)dp * 64 + kb);
    f16x8 as1 = *(const f16x8*)(h2 + (size_t)sp * 64 + 32 + kb);
    f16x8 ad1 = *(const f16x8*)(h2 + (size_t)dp * 64 + 32 + kb);
    a0 = as0 * ad0;
    a1 = as1 * ad1;
  };

  auto compute = [&](int g, f16x8 a0, f16x8 a1) {
    float psum = 0.f;
#pragma unroll
    for (int tt = 0; tt < 8; tt++) {
      f32x4 acc = {c0[tt].x, c0[tt].y, c0[tt].z, c0[tt].w};
      acc = __builtin_amdgcn_mfma_f32_16x16x32_f16(afrag[tt][0], a0, acc, 0, 0, 0);
      acc = __builtin_amdgcn_mfma_f32_16x16x32_f16(afrag[tt][1], a1, acc, 0, 0, 0);
      psum += fmaxf(acc[0], 0.f) * w2v[tt].x + fmaxf(acc[1], 0.f) * w2v[tt].y
            + fmaxf(acc[2], 0.f) * w2v[tt].z + fmaxf(acc[3], 0.f) * w2v[tt].w;
    }
    psum += __shfl_xor(psum, 16, 64);
    psum += __shfl_xor(psum, 32, 64);
    if (l < 16) {
      int epos = g * 16 + l;
      if (epos < E) out[epos] = psum + b2v;
    }
  };

  f16x8 a0, a1, na0, na1;
  ldrows(g0, a0, a1);
  for (int g = g0; g < g1; g++) {
    if (g + 1 < g1) ldrows(g + 1, na0, na1);
    compute(g, a0, a1);
    a0 = na0; a1 = na1;
  }
}

// ---------------- launch ----------------
extern "C" void kernel_launch(void* const* d_in, const int* in_sizes, int n_in,
                              void* d_out, int out_size, void* d_ws, size_t ws_size,
                              hipStream_t stream) {
  const float* x   = (const float*)d_in[0];
  const int*   ei  = (const int*)d_in[1];
  const float* Wl1 = (const float*)d_in[2];
  const float* bl1 = (const float*)d_in[3];
  const float* Wr1 = (const float*)d_in[4];
  const float* Wl2 = (const float*)d_in[5];
  const float* bl2 = (const float*)d_in[6];
  const float* Wr2 = (const float*)d_in[7];
  const float* W1  = (const float*)d_in[8];
  const float* b1  = (const float*)d_in[9];
  const float* W2  = (const float*)d_in[10];
  const float* b2  = (const float*)d_in[11];
  const int N = in_sizes[0] / 64;
  const int E = in_sizes[1] / 2;
  const int* src = ei;
  const int* dstp = ei + E;

  char* w = (char*)d_ws;
  size_t off = 0;
  auto alloc = [&](size_t bytes) -> void* {
    void* p = w + off;
    off = (off + bytes + 255) & ~(size_t)255;
    return p;
  };
  int*      deg      = (int*)alloc((size_t)N * 4);
  int*      row      = (int*)alloc((size_t)(N + 1) * 4);
  int*      ex       = (int*)alloc((size_t)N * 4);
  int*      bsum     = (int*)alloc(1024 * 4);
  int*      cbcursor = (int*)alloc(512 * 4);
  int*      srcs     = (int*)alloc((size_t)E * 4);
  unsigned long long* ep = (unsigned long long*)alloc((size_t)E * 8);
  _Float16* f16buf   = (_Float16*)alloc((size_t)N * 64 * 2);   // x16 -> g16 -> h2
  _Float16* agg16    = (_Float16*)alloc((size_t)N * 64 * 2);   // aggX -> aggG
  _Float16* h1_16    = (_Float16*)alloc((size_t)N * 128 * 2);

  const int ncb = (N + 255) >> 8;

  hipMemsetAsync(deg, 0, (size_t)N * 4, stream);
  int n4 = N * 16;
  int kag = (max(n4, E) + 255) / 256;
  kA_convert_hist<<<kag, 256, 0, stream>>>(x, f16buf, dstp, deg, n4, E);
  int nb = (N + 255) / 256;
  k_scan1<<<nb, 256, 0, stream>>>(deg, ex, bsum, N);
  k_scan2<<<1, 1024, 0, stream>>>(bsum, nb);
  k_scan3<<<nb, 256, 0, stream>>>(bsum, row, ex, N, E);
  k_cbinit<<<2, 256, 0, stream>>>(row, cbcursor, N, ncb);
  k_coarse<<<256, 256, 0, stream>>>(src, dstp, cbcursor, ep, E);
  k_fine_sort<<<ncb, 256, 0, stream>>>(ep, row, srcs, N, E);

  int ngrid = (N + 63) / 64;
  int ggrid = (N * 8 + 255) / 256;
  k_gather16<<<ggrid, 256, 0, stream>>>(f16buf, row, srcs, agg16, N);
  k_node_mfma<64, 128, 0><<<ngrid, 256, 0, stream>>>(
      agg16, f16buf, Wl1, Wr1, bl1, nullptr, deg, h1_16, N);
  k_node_mfma<128, 64, 1><<<ngrid, 256, 0, stream>>>(
      h1_16, nullptr, Wl2, nullptr, nullptr, nullptr, nullptr, f16buf, N);
  k_gather16<<<ggrid, 256, 0, stream>>>(f16buf, row, srcs, agg16, N);
  k_node_mfma<128, 64, 2><<<ngrid, 256, 0, stream>>>(
      h1_16, nullptr, Wr2, nullptr, bl2, agg16, deg, f16buf, N);
  k_edge_mfma<<<4096, 256, 0, stream>>>(f16buf, src, dstp, W1, W2, b1, b2,
                                        (float*)d_out, E);
}